// Round 2
// baseline (381.387 us; speedup 1.0000x reference)
//
#include <hip/hip_runtime.h>

#define BATCH   8
#define CDIM    32
#define KLBL    64
#define LDSPAD  33                    // bank = (lab + c) % 32 -> spread by label
#define PSTRIDE (KLBL * CDIM + KLBL)  // 2112 floats per partial record
#define MAXBPB  64

// ---------------- Kernel 1: per-batch segment partial sums ----------------
// grid = (bpb, BATCH), block = 256. Each block writes its own partial record.
__global__ __launch_bounds__(256) void seg_sum_kernel(
    const float* __restrict__ pred,    // [B][C][N]
    const int*   __restrict__ label,   // [B][N]
    float* __restrict__ partial,       // [B][bpb][PSTRIDE]
    int N, int bpb) {
  __shared__ float s_sums[KLBL * LDSPAD];
  __shared__ float s_counts[KLBL];

  for (int i = threadIdx.x; i < KLBL * LDSPAD; i += 256) s_sums[i] = 0.f;
  if (threadIdx.x < KLBL) s_counts[threadIdx.x] = 0.f;
  __syncthreads();

  const int b = blockIdx.y;
  const float* __restrict__ pb = pred + (size_t)b * CDIM * N;
  const int*   __restrict__ lb = label + (size_t)b * N;
  const int ngroups = N >> 2;
  const int stride  = gridDim.x * 256;

  for (int g = blockIdx.x * 256 + threadIdx.x; g < ngroups; g += stride) {
    const int4 l4 = *reinterpret_cast<const int4*>(lb + 4 * g);
    float4 pv[CDIM];
#pragma unroll
    for (int c = 0; c < CDIM; ++c)
      pv[c] = *reinterpret_cast<const float4*>(pb + (size_t)c * N + 4 * g);
    // keep the 32 dwordx4 loads clustered ABOVE the atomic chain
    __builtin_amdgcn_sched_barrier(0);

    atomicAdd(&s_counts[l4.x], 1.f);
    atomicAdd(&s_counts[l4.y], 1.f);
    atomicAdd(&s_counts[l4.z], 1.f);
    atomicAdd(&s_counts[l4.w], 1.f);
#pragma unroll
    for (int c = 0; c < CDIM; ++c) {
      atomicAdd(&s_sums[l4.x * LDSPAD + c], pv[c].x);
      atomicAdd(&s_sums[l4.y * LDSPAD + c], pv[c].y);
      atomicAdd(&s_sums[l4.z * LDSPAD + c], pv[c].z);
      atomicAdd(&s_sums[l4.w * LDSPAD + c], pv[c].w);
    }
  }

  // scalar tail for N % 4 (block x==0 only)
  if (blockIdx.x == 0) {
    for (int n = (ngroups << 2) + threadIdx.x; n < N; n += 256) {
      const int lab = lb[n];
      atomicAdd(&s_counts[lab], 1.f);
      for (int c = 0; c < CDIM; ++c)
        atomicAdd(&s_sums[lab * LDSPAD + c], pb[(size_t)c * N + n]);
    }
  }
  __syncthreads();

  // flush: plain coalesced stores (no global atomics)
  float* dst = partial + ((size_t)b * bpb + blockIdx.x) * PSTRIDE;
  for (int i = threadIdx.x; i < KLBL * CDIM; i += 256)
    dst[i] = s_sums[(i >> 5) * LDSPAD + (i & 31)];
  if (threadIdx.x < KLBL)
    dst[KLBL * CDIM + threadIdx.x] = s_counts[threadIdx.x];
}

// ---------------- Kernel 2: reduce partials ----------------
// grid = ceil(B*PSTRIDE/256), block = 256
__global__ __launch_bounds__(256) void reduce_kernel(
    const float* __restrict__ partial,  // [B][bpb][PSTRIDE]
    float* __restrict__ red,            // [B][PSTRIDE]
    int bpb) {
  const int idx = blockIdx.x * 256 + threadIdx.x;
  const int b = idx / PSTRIDE;
  const int i = idx - b * PSTRIDE;
  if (b >= BATCH) return;
  const float* src = partial + (size_t)b * bpb * PSTRIDE + i;
  float acc = 0.f;
  for (int j = 0; j < bpb; ++j) acc += src[(size_t)j * PSTRIDE];
  red[idx] = acc;
}

// ---------------- Kernel 3: centers -> pairwise hinge loss ----------------
// grid = BATCH, block = 256
__global__ __launch_bounds__(256) void loss_kernel(
    const float* __restrict__ red,  // [B][PSTRIDE]
    float* __restrict__ out) {      // scalar (pre-zeroed)
  const int b = blockIdx.x;
  __shared__ float s_center[KLBL * CDIM];  // [k][c]
  __shared__ float s_red[256];
  const float* sb = red + (size_t)b * PSTRIDE;

  for (int i = threadIdx.x; i < KLBL * CDIM; i += 256) {
    const float cnt = fmaxf(sb[KLBL * CDIM + (i >> 5)], 1.0f);
    s_center[i] = sb[i] / cnt;
  }
  __syncthreads();

  float acc = 0.f;
  for (int p = threadIdx.x; p < CDIM * CDIM; p += 256) {
    const int i = p >> 5, j = p & 31;
    float g = 0.f, ni = 0.f, nj = 0.f;
#pragma unroll
    for (int k = 0; k < KLBL; ++k) {
      const float ci = s_center[k * CDIM + i];  // broadcast within half-wave
      const float cj = s_center[k * CDIM + j];  // stride-1 -> conflict-free
      g  += ci * cj;
      ni += ci * ci;
      nj += cj * cj;
    }
    float sq = fmaxf(ni + nj - 2.f * g, 0.f);
    const float dist = (sq > 0.f) ? sqrtf(sq) : 0.f;
    const float h = fmaxf(3.0f - dist, 0.f);  // 2*D_DIST = 3.0
    acc += h * h;
  }

  s_red[threadIdx.x] = acc;
  __syncthreads();
  for (int s = 128; s > 0; s >>= 1) {
    if (threadIdx.x < s) s_red[threadIdx.x] += s_red[threadIdx.x + s];
    __syncthreads();
  }
  if (threadIdx.x == 0)
    atomicAdd(out, s_red[0] / (2.0f * (float)KLBL * ((float)KLBL - 1.0f)));
}

// ---------------- launch ----------------
extern "C" void kernel_launch(void* const* d_in, const int* in_sizes, int n_in,
                              void* d_out, int out_size, void* d_ws, size_t ws_size,
                              hipStream_t stream) {
  const float* pred  = (const float*)d_in[0];
  const int*   label = (const int*)d_in[1];
  float* out = (float*)d_out;

  const int N = in_sizes[1] / BATCH;  // 200000

  // ws layout: [partials: B*bpb*PSTRIDE][red: B*PSTRIDE]
  const size_t per_set = (size_t)BATCH * PSTRIDE * sizeof(float);  // 67.6 KB
  size_t sets = ws_size / per_set;
  int bpb = (sets > 1) ? (int)(sets - 1) : 1;
  if (bpb > MAXBPB) bpb = MAXBPB;

  float* partial = (float*)d_ws;
  float* red     = partial + (size_t)BATCH * bpb * PSTRIDE;

  hipMemsetAsync(d_out, 0, sizeof(float), stream);

  dim3 grid1(bpb, BATCH);
  seg_sum_kernel<<<grid1, 256, 0, stream>>>(pred, label, partial, N, bpb);

  const int nred = BATCH * PSTRIDE;
  reduce_kernel<<<(nred + 255) / 256, 256, 0, stream>>>(partial, red, bpb);
  loss_kernel<<<BATCH, 256, 0, stream>>>(red, out);
}